// Round 1
// baseline (1255.598 us; speedup 1.0000x reference)
//
#include <hip/hip_runtime.h>
#include <stdint.h>

// ---------------------------------------------------------------------------
// ColorHead: quantize -> 11x11 mode pool -> (1x1conv+BN+LReLU)x2 ->
//            6-level stride-3 conv pyramid + nearest upsample + grouped 1x1
//            + per-level train-BN -> accumulated score (8,32,512,512) fp32.
// ---------------------------------------------------------------------------

#define B_    8
#define HW_   512
#define NPX   2097152          // 8*512*512
#define NINV  (1.0f/2097152.0f)

// ---- workspace layout (bytes) ----
#define OFF_STATS 0            // float stats[4096]
#define OFF_PART  16384        // float part[4096][32]
#define OFF_MODE  540672       // uint8 mode[8*3*512*512]
#define OFF_PREP  6832128      // uint16 (bf16) prep[8*16*512*512]
#define OFF_D1    73940992     // float d1[8*16*171*171]
#define OFF_D2    88912384     // float d2[8*16*57*57]
#define OFF_D3    90575872     // float d3[8*16*19*19]
#define OFF_D4    90760704     // float d4[8*16*7*7]
#define OFF_D5    90785792     // float d5[8*16*3*3]
#define OFF_D6    90790400     // float d6[8*16*1*1]

// ---- stats region (float indices) ----
#define S_PRE1    0     // 16
#define S2_PRE1   16    // 16
#define S_H1      32    // 16
#define S_H1H1    48    // 136 (upper tri raw second moments)
#define S_PREP    184   // 16
#define S2_PREP   200   // 16
#define S_Z1      216   // 16
#define S2_Z1     232   // 16
#define S_PZ1     248   // 16
#define S_LVLBASE 264   // levels 2..6: 48 each {Sz,Sz2,Szz}
#define P_A1      512   // 48
#define P_B1      560   // 16
#define P_A2      576   // 256
#define P_B2      832   // 16
#define P_AFF     848   // 6*32*3 = 576

__device__ __forceinline__ uint16_t f2bf(float f) {
  uint32_t u = __float_as_uint(f);
  u += 0x7FFFu + ((u >> 16) & 1u);
  return (uint16_t)(u >> 16);
}
__device__ __forceinline__ float bf2f(uint16_t u) {
  return __uint_as_float(((uint32_t)u) << 16);
}

__device__ __forceinline__ float wave_red(float v) {
  v += __shfl_down(v, 32); v += __shfl_down(v, 16); v += __shfl_down(v, 8);
  v += __shfl_down(v, 4);  v += __shfl_down(v, 2);  v += __shfl_down(v, 1);
  return v;
}

// block = 256 threads. Reduce K per-thread partials, then atomic/store.
template<int K, bool ATOMIC>
__device__ __forceinline__ void block_red(float* acc, float* dst, float* lds) {
  int lane = threadIdx.x & 63, wid = threadIdx.x >> 6;
#pragma unroll
  for (int k = 0; k < K; ++k) {
    float v = wave_red(acc[k]);
    if (lane == 0) lds[wid * K + k] = v;
  }
  __syncthreads();
  if ((int)threadIdx.x < K) {
    float s = lds[threadIdx.x] + lds[K + threadIdx.x] + lds[2 * K + threadIdx.x] + lds[3 * K + threadIdx.x];
    if (ATOMIC) atomicAdd(&dst[threadIdx.x], s);
    else        dst[threadIdx.x] = s;
  }
}

// ---------------------------------------------------------------------------
// K1: quantize + 11x11 reflect-padded mode pool.
// Per-thread vertical sliding window; 17 byte-counters packed in 5 u32 VGPRs.
// tile: 256 output cols x 32 output rows per block.
// ---------------------------------------------------------------------------
__global__ __launch_bounds__(256) void k_mode(const float* __restrict__ x,
                                              uint8_t* __restrict__ mode) {
  int bx = blockIdx.x;
  int rb = bx & 15, cb = (bx >> 4) & 1, pl = bx >> 5;  // 16 rowblk, 2 colblk, 24 planes
  __shared__ uint8_t tile[42][272];                    // 42 rows x 266 cols used
  const float* xp = x + (size_t)pl * 262144;
  int tid = threadIdx.x;
  for (int e = tid; e < 42 * 266; e += 256) {
    int lr = e / 266, lc = e - lr * 266;
    int gr = rb * 32 - 5 + lr; if (gr < 0) gr = -gr; else if (gr > 511) gr = 1022 - gr;
    int gc = cb * 256 - 5 + lc; if (gc < 0) gc = -gc; else if (gc > 511) gc = 1022 - gc;
    float v = xp[gr * 512 + gc];
    tile[lr][lc] = (uint8_t)(int)rintf((v * 255.0f) * 0.0625f);  // matches (x*255)/16 + RNE
  }
  __syncthreads();
  int t = tid;
  uint32_t h0 = 0, h1 = 0, h2 = 0, h3 = 0, h4 = 0;
#define ADDV(vv) { int v_ = (vv); uint32_t inc_ = 1u << ((v_ & 3) << 3); int w_ = v_ >> 2; \
    h0 += (w_ == 0) ? inc_ : 0u; h1 += (w_ == 1) ? inc_ : 0u; h2 += (w_ == 2) ? inc_ : 0u; \
    h3 += (w_ == 3) ? inc_ : 0u; h4 += (w_ == 4) ? inc_ : 0u; }
#define SUBV(vv) { int v_ = (vv); uint32_t inc_ = 1u << ((v_ & 3) << 3); int w_ = v_ >> 2; \
    h0 -= (w_ == 0) ? inc_ : 0u; h1 -= (w_ == 1) ? inc_ : 0u; h2 -= (w_ == 2) ? inc_ : 0u; \
    h3 -= (w_ == 3) ? inc_ : 0u; h4 -= (w_ == 4) ? inc_ : 0u; }
#define SCAN_STORE(OI) { uint32_t best_ = h0 & 255u; int bi_ = 0; uint32_t c_; \
    c_ = (h0 >> 8)  & 255u; if (c_ > best_) { best_ = c_; bi_ = 1; } \
    c_ = (h0 >> 16) & 255u; if (c_ > best_) { best_ = c_; bi_ = 2; } \
    c_ = (h0 >> 24);        if (c_ > best_) { best_ = c_; bi_ = 3; } \
    c_ = h1 & 255u;         if (c_ > best_) { best_ = c_; bi_ = 4; } \
    c_ = (h1 >> 8)  & 255u; if (c_ > best_) { best_ = c_; bi_ = 5; } \
    c_ = (h1 >> 16) & 255u; if (c_ > best_) { best_ = c_; bi_ = 6; } \
    c_ = (h1 >> 24);        if (c_ > best_) { best_ = c_; bi_ = 7; } \
    c_ = h2 & 255u;         if (c_ > best_) { best_ = c_; bi_ = 8; } \
    c_ = (h2 >> 8)  & 255u; if (c_ > best_) { best_ = c_; bi_ = 9; } \
    c_ = (h2 >> 16) & 255u; if (c_ > best_) { best_ = c_; bi_ = 10; } \
    c_ = (h2 >> 24);        if (c_ > best_) { best_ = c_; bi_ = 11; } \
    c_ = h3 & 255u;         if (c_ > best_) { best_ = c_; bi_ = 12; } \
    c_ = (h3 >> 8)  & 255u; if (c_ > best_) { best_ = c_; bi_ = 13; } \
    c_ = (h3 >> 16) & 255u; if (c_ > best_) { best_ = c_; bi_ = 14; } \
    c_ = (h3 >> 24);        if (c_ > best_) { best_ = c_; bi_ = 15; } \
    c_ = h4 & 255u;         if (c_ > best_) { best_ = c_; bi_ = 16; } \
    mode[OI] = (uint8_t)bi_; }
#pragma unroll
  for (int dy = 0; dy < 11; ++dy) {
#pragma unroll
    for (int dx = 0; dx < 11; ++dx) ADDV(tile[dy][t + dx]);
  }
  size_t ob = (size_t)pl * 262144 + (size_t)(rb * 32) * 512 + cb * 256 + t;
  SCAN_STORE(ob);
  for (int s = 1; s < 32; ++s) {
#pragma unroll
    for (int dx = 0; dx < 11; ++dx) { SUBV(tile[s - 1][t + dx]); ADDV(tile[s + 10][t + dx]); }
    SCAN_STORE(ob + (size_t)s * 512);
  }
#undef ADDV
#undef SUBV
#undef SCAN_STORE
}

// ---------------------------------------------------------------------------
// K2: stats of pre1 = pw1*xq + pb1 (sum, sumsq per channel). grid 512.
// ---------------------------------------------------------------------------
__global__ __launch_bounds__(256) void k_pre1stats(const uint8_t* __restrict__ mode,
                                                   const float* __restrict__ pw1,
                                                   const float* __restrict__ pb1,
                                                   float* __restrict__ stats) {
  float acc[32];
#pragma unroll
  for (int k = 0; k < 32; ++k) acc[k] = 0.f;
  int tid0 = blockIdx.x * 256 + threadIdx.x;
  for (int px = tid0; px < NPX; px += 131072) {
    int b = px >> 18, rem = px & 262143;
    float xq0 = mode[(b * 3 + 0) * 262144 + rem] * 0.0625f;
    float xq1 = mode[(b * 3 + 1) * 262144 + rem] * 0.0625f;
    float xq2 = mode[(b * 3 + 2) * 262144 + rem] * 0.0625f;
#pragma unroll
    for (int o = 0; o < 16; ++o) {
      float p = fmaf(pw1[o * 3], xq0, fmaf(pw1[o * 3 + 1], xq1, fmaf(pw1[o * 3 + 2], xq2, pb1[o])));
      acc[o] += p; acc[16 + o] = fmaf(p, p, acc[16 + o]);
    }
  }
  __shared__ float red[4 * 32];
  block_red<32, true>(acc, stats + S_PRE1, red);
}

// K3: BN1 affine -> A1 (16x3), B1 (16)
__global__ void k_bn1prep(float* stats, const float* pw1, const float* pb1,
                          const float* g1, const float* be1) {
  int o = threadIdx.x; if (o >= 16) return;
  float m = stats[S_PRE1 + o] * NINV;
  float var = stats[S2_PRE1 + o] * NINV - m * m;
  float s = g1[o] * rsqrtf(var + 1e-5f);
  stats[P_A1 + o * 3 + 0] = pw1[o * 3 + 0] * s;
  stats[P_A1 + o * 3 + 1] = pw1[o * 3 + 1] * s;
  stats[P_A1 + o * 3 + 2] = pw1[o * 3 + 2] * s;
  stats[P_B1 + o] = (pb1[o] - m) * s + be1[o];
}

// ---------------------------------------------------------------------------
// K4: h1 raw moments (16 sums + 136 upper-tri products). h1 recomputed. grid 512.
// ---------------------------------------------------------------------------
__global__ __launch_bounds__(256) void k_h1stats(const uint8_t* __restrict__ mode,
                                                 float* __restrict__ stats) {
  const float* A1 = stats + P_A1;
  const float* B1 = stats + P_B1;
  float acc[152];
#pragma unroll
  for (int k = 0; k < 152; ++k) acc[k] = 0.f;
  int tid0 = blockIdx.x * 256 + threadIdx.x;
  for (int px = tid0; px < NPX; px += 131072) {
    int b = px >> 18, rem = px & 262143;
    float xq0 = mode[(b * 3 + 0) * 262144 + rem] * 0.0625f;
    float xq1 = mode[(b * 3 + 1) * 262144 + rem] * 0.0625f;
    float xq2 = mode[(b * 3 + 2) * 262144 + rem] * 0.0625f;
    float h[16];
#pragma unroll
    for (int c = 0; c < 16; ++c) {
      float y = fmaf(A1[c * 3], xq0, fmaf(A1[c * 3 + 1], xq1, fmaf(A1[c * 3 + 2], xq2, B1[c])));
      h[c] = fmaxf(y, 0.01f * y);
      acc[c] += h[c];
    }
#pragma unroll
    for (int c = 0; c < 16; ++c) {
#pragma unroll
      for (int c2 = c; c2 < 16; ++c2) {
        int idx = 16 * c - (c * (c - 1)) / 2 + (c2 - c);
        acc[16 + idx] = fmaf(h[c], h[c2], acc[16 + idx]);
      }
    }
  }
  __shared__ float red[4 * 152];
  block_red<152, true>(acc, stats + S_H1, red);
}

// K5: BN2 affine via h1 second moments -> A2 (16x16), B2 (16)
__global__ void k_bn2prep(float* stats, const float* pw2, const float* pb2,
                          const float* g2, const float* be2) {
  int o = threadIdx.x; if (o >= 16) return;
  float mu[16];
#pragma unroll
  for (int c = 0; c < 16; ++c) mu[c] = stats[S_H1 + c] * NINV;
  float s1 = 0.f;
#pragma unroll
  for (int c = 0; c < 16; ++c) s1 += pw2[o * 16 + c] * mu[c];
  float e2 = 0.f;
#pragma unroll
  for (int c = 0; c < 16; ++c) {
#pragma unroll
    for (int c2 = 0; c2 < 16; ++c2) {
      int lo = c < c2 ? c : c2, hi = c < c2 ? c2 : c;
      int idx = 16 * lo - (lo * (lo - 1)) / 2 + (hi - lo);
      e2 = fmaf(pw2[o * 16 + c] * pw2[o * 16 + c2], stats[S_H1H1 + idx] * NINV, e2);
    }
  }
  float var = e2 - s1 * s1;          // pb2 cancels
  float mean = s1 + pb2[o];
  float s = g2[o] * rsqrtf(var + 1e-5f);
#pragma unroll
  for (int c = 0; c < 16; ++c) stats[P_A2 + o * 16 + c] = pw2[o * 16 + c] * s;
  stats[P_B2 + o] = (pb2[o] - mean) * s + be2[o];
}

// ---------------------------------------------------------------------------
// K6: prep = lrelu(A2*h1+B2), stored bf16; also per-group sum/sumsq partials.
// grid 4096 = (b, row j); thread t -> cols 2t, 2t+1.
// ---------------------------------------------------------------------------
__global__ __launch_bounds__(256) void k_prep(const uint8_t* __restrict__ mode,
                                              const float* __restrict__ stats,
                                              uint16_t* __restrict__ prep,
                                              float* __restrict__ part) {
  int bx = blockIdx.x; int b = bx >> 9, j = bx & 511;
  const float* A1 = stats + P_A1; const float* B1 = stats + P_B1;
  const float* A2 = stats + P_A2; const float* B2 = stats + P_B2;
  int i0 = threadIdx.x * 2;
  float acc[32];
#pragma unroll
  for (int k = 0; k < 32; ++k) acc[k] = 0.f;
  uint32_t packed[16];
#pragma unroll
  for (int half = 0; half < 2; ++half) {
    int i = i0 + half;
    int rem = j * 512 + i;
    float xq0 = mode[(b * 3 + 0) * 262144 + rem] * 0.0625f;
    float xq1 = mode[(b * 3 + 1) * 262144 + rem] * 0.0625f;
    float xq2 = mode[(b * 3 + 2) * 262144 + rem] * 0.0625f;
    float h[16];
#pragma unroll
    for (int c = 0; c < 16; ++c) {
      float y = fmaf(A1[c * 3], xq0, fmaf(A1[c * 3 + 1], xq1, fmaf(A1[c * 3 + 2], xq2, B1[c])));
      h[c] = fmaxf(y, 0.01f * y);
    }
#pragma unroll
    for (int o = 0; o < 16; ++o) {
      float y = B2[o];
#pragma unroll
      for (int c = 0; c < 16; ++c) y = fmaf(A2[o * 16 + c], h[c], y);
      float p = fmaxf(y, 0.01f * y);
      acc[o] += p; acc[16 + o] = fmaf(p, p, acc[16 + o]);
      uint32_t bv = f2bf(p);
      if (half == 0) packed[o] = bv; else packed[o] |= bv << 16;
    }
  }
  uint32_t* p32 = (uint32_t*)prep;
#pragma unroll
  for (int o = 0; o < 16; ++o)
    p32[(((size_t)(b * 16 + o) * 512 + j) * 512 + i0) >> 1] = packed[o];
  __shared__ float red[4 * 32];
  block_red<32, false>(acc, part + (size_t)bx * 32, red);
}

// K6b: reduce 4096x32 partials -> prep stats
__global__ void k_part_reduce(const float* __restrict__ part, float* __restrict__ stats) {
  int t = threadIdx.x; int k = t & 31, c = t >> 5;  // c in 0..7
  float s = 0.f;
  for (int blk = c * 512; blk < (c + 1) * 512; ++blk) s += part[(size_t)blk * 32 + k];
  __shared__ float red[256];
  red[t] = s; __syncthreads();
  if (t < 32) {
    float tot = 0.f;
    for (int cc = 0; cc < 8; ++cc) tot += red[cc * 32 + t];
    stats[S_PREP + t] = tot;   // [0..16)=sum, [16..32)=sumsq (consecutive slots)
  }
}

// ---------------------------------------------------------------------------
// K7: conv 3x3 stride 3 pad 1, 16->16 channels. One block per (b, out row).
// ---------------------------------------------------------------------------
template<bool BF> struct itype { using T = float; };
template<> struct itype<true> { using T = uint16_t; };

template<int HIN, int WIN, int HOUT, int WOUT, bool BF>
__global__ __launch_bounds__(256) void k_conv(const void* __restrict__ inv,
                                              float* __restrict__ out,
                                              const float* __restrict__ dw) {
  using IT = typename itype<BF>::T;
  const IT* in = (const IT*)inv;
  __shared__ IT tile[3][16][WIN + 2];
  int bx = blockIdx.x; int r = bx % HOUT, b = bx / HOUT;
  int tid = threadIdx.x;
  for (int e = tid; e < 48; e += 256) { tile[e / 16][e & 15][0] = (IT)0; tile[e / 16][e & 15][WIN + 1] = (IT)0; }
  for (int e = tid; e < 3 * 16 * WIN; e += 256) {
    int ky = e / (16 * WIN); int rem = e - ky * (16 * WIN); int ic = rem / WIN; int col = rem - ic * WIN;
    int gr = 3 * r - 1 + ky;
    IT v = (IT)0;
    if (gr >= 0 && gr < HIN) v = in[((size_t)(b * 16 + ic) * HIN + gr) * WIN + col];
    tile[ky][ic][col + 1] = v;
  }
  __syncthreads();
  int c = tid;
  if (c < WOUT) {
    float acc[16];
#pragma unroll
    for (int o = 0; o < 16; ++o) acc[o] = 0.f;
#pragma unroll
    for (int ic = 0; ic < 16; ++ic) {
      float v[9];
#pragma unroll
      for (int ky = 0; ky < 3; ++ky) {
#pragma unroll
        for (int kx = 0; kx < 3; ++kx) {
          IT raw = tile[ky][ic][3 * c + kx];
          if constexpr (BF) v[ky * 3 + kx] = __uint_as_float(((uint32_t)raw) << 16);
          else              v[ky * 3 + kx] = (float)raw;
        }
      }
#pragma unroll
      for (int o = 0; o < 16; ++o) {
        const float* w = dw + (o * 16 + ic) * 9;
#pragma unroll
        for (int tp = 0; tp < 9; ++tp) acc[o] = fmaf(v[tp], w[tp], acc[o]);
      }
    }
#pragma unroll
    for (int o = 0; o < 16; ++o)
      out[((size_t)(b * 16 + o) * HOUT + r) * WOUT + c] = acc[o];
  }
}

// ---------------------------------------------------------------------------
// K8: level-1 stats: Sz1, Sz1^2, S(prep*z1) over dst grid. grid 512.
// ---------------------------------------------------------------------------
__global__ __launch_bounds__(256) void k_corr1(const uint16_t* __restrict__ prep,
                                               const float* __restrict__ d1,
                                               float* __restrict__ stats) {
  int bx = blockIdx.x; int b = bx >> 6, band = bx & 63;
  float acc[48];
#pragma unroll
  for (int k = 0; k < 48; ++k) acc[k] = 0.f;
  for (int jj = 0; jj < 8; ++jj) {
    int j = band * 8 + jj;
    int r1 = (j * 171) >> 9;
    for (int i = threadIdx.x; i < 512; i += 256) {
      int c1 = (i * 171) >> 9;
#pragma unroll
      for (int g = 0; g < 16; ++g) {
        float p = bf2f(prep[((size_t)(b * 16 + g) * 512 + j) * 512 + i]);
        float z = d1[((size_t)(b * 16 + g) * 171 + r1) * 171 + c1];
        acc[g] += z; acc[16 + g] = fmaf(z, z, acc[16 + g]); acc[32 + g] = fmaf(p, z, acc[32 + g]);
      }
    }
  }
  __shared__ float red[4 * 48];
  block_red<48, true>(acc, stats + S_Z1, red);
}

// ---------------------------------------------------------------------------
// K9: pair stats for level l>=2: Sz, Sz^2, S(z_{l-1} z_l) over dst grid.
// grid 512 = (jq 4, b 8, g 16).
// ---------------------------------------------------------------------------
template<int HP, int HZ>
__global__ __launch_bounds__(256) void k_pair(const float* __restrict__ dp,
                                              const float* __restrict__ dz,
                                              float* __restrict__ dst) {
  int bx = blockIdx.x;
  int g = bx & 15, b = (bx >> 4) & 7, jq = bx >> 7;
  const float* dpp = dp + (size_t)(b * 16 + g) * HP * HP;
  const float* dzp = dz + (size_t)(b * 16 + g) * HZ * HZ;
  float a1 = 0.f, a2 = 0.f, a3 = 0.f;
  for (int j = jq * 128; j < jq * 128 + 128; ++j) {
    int r1 = (j * HP) >> 9, r2 = (j * HZ) >> 9;
    const float* rp = dpp + r1 * HP;
    const float* rz = dzp + r2 * HZ;
    for (int i = threadIdx.x; i < 512; i += 256) {
      int c1 = (i * HP) >> 9, c2 = (i * HZ) >> 9;
      float zp = rp[c1], zz = rz[c2];
      a1 += zz; a2 = fmaf(zz, zz, a2); a3 = fmaf(zp, zz, a3);
    }
  }
  a1 = wave_red(a1); a2 = wave_red(a2); a3 = wave_red(a3);
  __shared__ float red[12];
  int lane = threadIdx.x & 63, wid = threadIdx.x >> 6;
  if (!lane) { red[wid * 3] = a1; red[wid * 3 + 1] = a2; red[wid * 3 + 2] = a3; }
  __syncthreads();
  if (threadIdx.x < 3) {
    float s = red[threadIdx.x] + red[3 + threadIdx.x] + red[6 + threadIdx.x] + red[9 + threadIdx.x];
    atomicAdd(&dst[threadIdx.x * 16 + g], s);
  }
}

// K10: per-level BN affine: a0=s*sw0, a1=s*sw1, b = bs - mean*s
__global__ void k_bnLprep(float* stats, const float* sw, const float* gs, const float* bs) {
  int t = threadIdx.x; if (t >= 192) return;
  int lvl = t >> 5, ch = t & 31, g = ch >> 1, o = ch & 1;
  float Sp, Sp2, Sz, Sz2, Spz;
  if (lvl == 0) {
    Sp = stats[S_PREP + g]; Sp2 = stats[S2_PREP + g];
    Sz = stats[S_Z1 + g];   Sz2 = stats[S2_Z1 + g]; Spz = stats[S_PZ1 + g];
  } else {
    int base = S_LVLBASE + (lvl - 1) * 48;
    Sz = stats[base + g]; Sz2 = stats[base + 16 + g]; Spz = stats[base + 32 + g];
    if (lvl == 1) { Sp = stats[S_Z1 + g]; Sp2 = stats[S2_Z1 + g]; }
    else { int pb = S_LVLBASE + (lvl - 2) * 48; Sp = stats[pb + g]; Sp2 = stats[pb + 16 + g]; }
  }
  float mp = Sp * NINV, mz = Sz * NINV;
  float ep2 = Sp2 * NINV, ez2 = Sz2 * NINV, epz = Spz * NINV;
  float w0 = sw[g * 4 + o * 2], w1 = sw[g * 4 + o * 2 + 1];
  float mean = w0 * mp + w1 * mz;
  float e2 = w0 * w0 * ep2 + 2.f * w0 * w1 * epz + w1 * w1 * ez2;
  float var = e2 - mean * mean;
  float s = gs[ch] * rsqrtf(var + 1e-5f);
  float* a = stats + P_AFF + (lvl * 32 + ch) * 3;
  a[0] = s * w0; a[1] = s * w1; a[2] = bs[ch] - mean * s;
}

// ---------------------------------------------------------------------------
// K11: fused score: all 6 levels, one pass. grid 4096 = (b, row j).
// ---------------------------------------------------------------------------
__global__ __launch_bounds__(256) void k_score(const uint16_t* __restrict__ prep,
    const float* __restrict__ d1, const float* __restrict__ d2, const float* __restrict__ d3,
    const float* __restrict__ d4, const float* __restrict__ d5, const float* __restrict__ d6,
    const float* __restrict__ stats, float* __restrict__ out) {
  __shared__ float zrow[4128];
  int bx = blockIdx.x; int b = bx >> 9, j = bx & 511;
  int tid = threadIdx.x;
  { int r = (j * 171) >> 9; for (int e = tid; e < 16 * 171; e += 256) { int g = e / 171, c = e - g * 171; zrow[e]        = d1[((size_t)(b * 16 + g) * 171 + r) * 171 + c]; } }
  { int r = (j * 57)  >> 9; for (int e = tid; e < 16 * 57;  e += 256) { int g = e / 57,  c = e - g * 57;  zrow[2736 + e] = d2[((size_t)(b * 16 + g) * 57  + r) * 57  + c]; } }
  { int r = (j * 19)  >> 9; for (int e = tid; e < 16 * 19;  e += 256) { int g = e / 19,  c = e - g * 19;  zrow[3648 + e] = d3[((size_t)(b * 16 + g) * 19  + r) * 19  + c]; } }
  { int r = (j * 7)   >> 9; for (int e = tid; e < 16 * 7;   e += 256) { int g = e / 7,   c = e - g * 7;   zrow[3952 + e] = d4[((size_t)(b * 16 + g) * 7   + r) * 7   + c]; } }
  { int r = (j * 3)   >> 9; for (int e = tid; e < 16 * 3;   e += 256) { int g = e / 3,   c = e - g * 3;   zrow[4064 + e] = d5[((size_t)(b * 16 + g) * 3   + r) * 3   + c]; } }
  { for (int e = tid; e < 16; e += 256) zrow[4112 + e] = d6[b * 16 + e]; }
  __syncthreads();
  const float* af = stats + P_AFF;
  for (int i = tid; i < 512; i += 256) {
    int c1 = (i * 171) >> 9, c2 = (i * 57) >> 9, c3 = (i * 19) >> 9, c4 = (i * 7) >> 9, c5 = (i * 3) >> 9;
#pragma unroll
    for (int g = 0; g < 16; ++g) {
      float p = bf2f(prep[((size_t)(b * 16 + g) * 512 + j) * 512 + i]);
      float z1 = zrow[g * 171 + c1], z2 = zrow[2736 + g * 57 + c2], z3 = zrow[3648 + g * 19 + c3];
      float z4 = zrow[3952 + g * 7 + c4], z5 = zrow[4064 + g * 3 + c5], z6 = zrow[4112 + g];
      float prev = p, o0 = 0.f, o1 = 0.f;
#define LVLSTEP(L, ZV) { const float* a = af + ((L) * 32 + 2 * g) * 3; \
      float y0 = fmaf(a[0], prev, fmaf(a[1], (ZV), a[2])); o0 += fmaxf(y0, 0.01f * y0); \
      float y1 = fmaf(a[3], prev, fmaf(a[4], (ZV), a[5])); o1 += fmaxf(y1, 0.01f * y1); \
      prev = (ZV); }
      LVLSTEP(0, z1) LVLSTEP(1, z2) LVLSTEP(2, z3) LVLSTEP(3, z4) LVLSTEP(4, z5) LVLSTEP(5, z6)
#undef LVLSTEP
      size_t ob = ((size_t)(b * 32 + 2 * g) * 512 + j) * 512 + i;
      out[ob] = o0; out[ob + 262144] = o1;
    }
  }
}

// ---------------------------------------------------------------------------
extern "C" void kernel_launch(void* const* d_in, const int* in_sizes, int n_in,
                              void* d_out, int out_size, void* d_ws, size_t ws_size,
                              hipStream_t stream) {
  const float* x   = (const float*)d_in[0];
  const float* pw1 = (const float*)d_in[1];
  const float* pb1 = (const float*)d_in[2];
  const float* g1  = (const float*)d_in[3];
  const float* be1 = (const float*)d_in[4];
  const float* pw2 = (const float*)d_in[5];
  const float* pb2 = (const float*)d_in[6];
  const float* g2  = (const float*)d_in[7];
  const float* be2 = (const float*)d_in[8];
  const float* dw  = (const float*)d_in[9];
  const float* sw  = (const float*)d_in[10];
  const float* gs  = (const float*)d_in[11];
  const float* bs  = (const float*)d_in[12];
  char* ws = (char*)d_ws;
  float*    stats = (float*)(ws + OFF_STATS);
  float*    part  = (float*)(ws + OFF_PART);
  uint8_t*  mode  = (uint8_t*)(ws + OFF_MODE);
  uint16_t* prep  = (uint16_t*)(ws + OFF_PREP);
  float* d1 = (float*)(ws + OFF_D1);
  float* d2 = (float*)(ws + OFF_D2);
  float* d3 = (float*)(ws + OFF_D3);
  float* d4 = (float*)(ws + OFF_D4);
  float* d5 = (float*)(ws + OFF_D5);
  float* d6 = (float*)(ws + OFF_D6);
  float* out = (float*)d_out;

  hipMemsetAsync(stats, 0, 16384, stream);
  k_mode<<<768, 256, 0, stream>>>(x, mode);
  k_pre1stats<<<512, 256, 0, stream>>>(mode, pw1, pb1, stats);
  k_bn1prep<<<1, 64, 0, stream>>>(stats, pw1, pb1, g1, be1);
  k_h1stats<<<512, 256, 0, stream>>>(mode, stats);
  k_bn2prep<<<1, 64, 0, stream>>>(stats, pw2, pb2, g2, be2);
  k_prep<<<4096, 256, 0, stream>>>(mode, stats, prep, part);
  k_part_reduce<<<1, 256, 0, stream>>>(part, stats);
  k_conv<512, 512, 171, 171, true><<<8 * 171, 256, 0, stream>>>(prep, d1, dw);
  k_corr1<<<512, 256, 0, stream>>>(prep, d1, stats);
  k_conv<171, 171, 57, 57, false><<<8 * 57, 256, 0, stream>>>(d1, d2, dw);
  k_pair<171, 57><<<512, 256, 0, stream>>>(d1, d2, stats + S_LVLBASE + 0 * 48);
  k_conv<57, 57, 19, 19, false><<<8 * 19, 256, 0, stream>>>(d2, d3, dw);
  k_pair<57, 19><<<512, 256, 0, stream>>>(d2, d3, stats + S_LVLBASE + 1 * 48);
  k_conv<19, 19, 7, 7, false><<<8 * 7, 256, 0, stream>>>(d3, d4, dw);
  k_pair<19, 7><<<512, 256, 0, stream>>>(d3, d4, stats + S_LVLBASE + 2 * 48);
  k_conv<7, 7, 3, 3, false><<<8 * 3, 256, 0, stream>>>(d4, d5, dw);
  k_pair<7, 3><<<512, 256, 0, stream>>>(d4, d5, stats + S_LVLBASE + 3 * 48);
  k_conv<3, 3, 1, 1, false><<<8 * 1, 256, 0, stream>>>(d5, d6, dw);
  k_pair<3, 1><<<512, 256, 0, stream>>>(d5, d6, stats + S_LVLBASE + 4 * 48);
  k_bnLprep<<<1, 256, 0, stream>>>(stats, sw, gs, bs);
  k_score<<<4096, 256, 0, stream>>>(prep, d1, d2, d3, d4, d5, d6, stats, out);
}

// Round 2
// 1023.856 us; speedup vs baseline: 1.2263x; 1.2263x over previous
//
#include <hip/hip_runtime.h>
#include <stdint.h>

// ---------------------------------------------------------------------------
// ColorHead: quantize -> 11x11 mode pool -> (1x1conv+BN+LReLU)x2 ->
//            6-level stride-3 conv pyramid + nearest upsample + grouped 1x1
//            + per-level train-BN -> accumulated score (8,32,512,512) fp32.
// R1: prepare stage reduced to 4913-combo histogram + LUT; k_score rewritten
//     wave-per-g with register-resident affines.
// ---------------------------------------------------------------------------

#define NPX   2097152          // 8*512*512
#define NINV  (1.0f/2097152.0f)

// ---- workspace layout (bytes) ----
#define OFF_STATS 0            // float stats[4096]
#define OFF_HIST  16384        // uint32 hist[4913]
#define OFF_LUT   36864        // uint32 lut[4913*8]  (16 bf16 per combo)
#define OFF_MODE  194560       // uint8 mode[8*3*512*512]
#define OFF_PREP  6486016      // uint16 (bf16) prep[8*16*512*512]
#define OFF_D1    73594880     // float d1[8*16*171*171]
#define OFF_D2    88566272     // float d2[8*16*57*57]
#define OFF_D3    90229760     // float d3[8*16*19*19]
#define OFF_D4    90414592     // float d4[8*16*7*7]
#define OFF_D5    90439680     // float d5[8*16*3*3]
#define OFF_D6    90444288     // float d6[8*16*1*1]

// ---- stats region (float indices) ----
#define S_PRE1    0     // 16
#define S2_PRE1   16    // 16
#define S_H1      32    // 16
#define S_H1H1    48    // 136 (upper tri raw second moments)
#define S_PREP    184   // 16
#define S2_PREP   200   // 16
#define S_Z1      216   // 16
#define S2_Z1     232   // 16
#define S_PZ1     248   // 16
#define S_LVLBASE 264   // levels 2..6: 48 each {Sz,Sz2,Szz}
#define P_A1      512   // 48
#define P_B1      560   // 16
#define P_A2      576   // 256
#define P_B2      832   // 16
#define P_AFF     848   // 6*32*3 = 576

__device__ __forceinline__ uint32_t f2bf(float f) {
  uint32_t u = __float_as_uint(f);
  u += 0x7FFFu + ((u >> 16) & 1u);
  return u >> 16;
}
__device__ __forceinline__ float bf2f(uint32_t u) {
  return __uint_as_float(u << 16);
}

__device__ __forceinline__ float wave_red(float v) {
  v += __shfl_down(v, 32); v += __shfl_down(v, 16); v += __shfl_down(v, 8);
  v += __shfl_down(v, 4);  v += __shfl_down(v, 2);  v += __shfl_down(v, 1);
  return v;
}

// block = 256 threads. Reduce K per-thread partials, then atomic/store.
template<int K, bool ATOMIC>
__device__ __forceinline__ void block_red(float* acc, float* dst, float* lds) {
  int lane = threadIdx.x & 63, wid = threadIdx.x >> 6;
#pragma unroll
  for (int k = 0; k < K; ++k) {
    float v = wave_red(acc[k]);
    if (lane == 0) lds[wid * K + k] = v;
  }
  __syncthreads();
  if ((int)threadIdx.x < K) {
    float s = lds[threadIdx.x] + lds[K + threadIdx.x] + lds[2 * K + threadIdx.x] + lds[3 * K + threadIdx.x];
    if (ATOMIC) atomicAdd(&dst[threadIdx.x], s);
    else        dst[threadIdx.x] = s;
  }
}

// ---------------------------------------------------------------------------
// K1: quantize + 11x11 reflect-padded mode pool.
// Per-thread vertical sliding window; 17 byte-counters packed in 5 u32 VGPRs.
// ---------------------------------------------------------------------------
__global__ __launch_bounds__(256) void k_mode(const float* __restrict__ x,
                                              uint8_t* __restrict__ mode) {
  int bx = blockIdx.x;
  int rb = bx & 15, cb = (bx >> 4) & 1, pl = bx >> 5;  // 16 rowblk, 2 colblk, 24 planes
  __shared__ uint8_t tile[42][272];
  const float* xp = x + (size_t)pl * 262144;
  int tid = threadIdx.x;
  for (int e = tid; e < 42 * 266; e += 256) {
    int lr = e / 266, lc = e - lr * 266;
    int gr = rb * 32 - 5 + lr; if (gr < 0) gr = -gr; else if (gr > 511) gr = 1022 - gr;
    int gc = cb * 256 - 5 + lc; if (gc < 0) gc = -gc; else if (gc > 511) gc = 1022 - gc;
    float v = xp[gr * 512 + gc];
    tile[lr][lc] = (uint8_t)(int)rintf((v * 255.0f) * 0.0625f);
  }
  __syncthreads();
  int t = tid;
  uint32_t h0 = 0, h1 = 0, h2 = 0, h3 = 0, h4 = 0;
#define ADDV(vv) { int v_ = (vv); uint32_t inc_ = 1u << ((v_ & 3) << 3); int w_ = v_ >> 2; \
    h0 += (w_ == 0) ? inc_ : 0u; h1 += (w_ == 1) ? inc_ : 0u; h2 += (w_ == 2) ? inc_ : 0u; \
    h3 += (w_ == 3) ? inc_ : 0u; h4 += (w_ == 4) ? inc_ : 0u; }
#define SUBV(vv) { int v_ = (vv); uint32_t inc_ = 1u << ((v_ & 3) << 3); int w_ = v_ >> 2; \
    h0 -= (w_ == 0) ? inc_ : 0u; h1 -= (w_ == 1) ? inc_ : 0u; h2 -= (w_ == 2) ? inc_ : 0u; \
    h3 -= (w_ == 3) ? inc_ : 0u; h4 -= (w_ == 4) ? inc_ : 0u; }
#define SCAN_STORE(OI) { uint32_t best_ = h0 & 255u; int bi_ = 0; uint32_t c_; \
    c_ = (h0 >> 8)  & 255u; if (c_ > best_) { best_ = c_; bi_ = 1; } \
    c_ = (h0 >> 16) & 255u; if (c_ > best_) { best_ = c_; bi_ = 2; } \
    c_ = (h0 >> 24);        if (c_ > best_) { best_ = c_; bi_ = 3; } \
    c_ = h1 & 255u;         if (c_ > best_) { best_ = c_; bi_ = 4; } \
    c_ = (h1 >> 8)  & 255u; if (c_ > best_) { best_ = c_; bi_ = 5; } \
    c_ = (h1 >> 16) & 255u; if (c_ > best_) { best_ = c_; bi_ = 6; } \
    c_ = (h1 >> 24);        if (c_ > best_) { best_ = c_; bi_ = 7; } \
    c_ = h2 & 255u;         if (c_ > best_) { best_ = c_; bi_ = 8; } \
    c_ = (h2 >> 8)  & 255u; if (c_ > best_) { best_ = c_; bi_ = 9; } \
    c_ = (h2 >> 16) & 255u; if (c_ > best_) { best_ = c_; bi_ = 10; } \
    c_ = (h2 >> 24);        if (c_ > best_) { best_ = c_; bi_ = 11; } \
    c_ = h3 & 255u;         if (c_ > best_) { best_ = c_; bi_ = 12; } \
    c_ = (h3 >> 8)  & 255u; if (c_ > best_) { best_ = c_; bi_ = 13; } \
    c_ = (h3 >> 16) & 255u; if (c_ > best_) { best_ = c_; bi_ = 14; } \
    c_ = (h3 >> 24);        if (c_ > best_) { best_ = c_; bi_ = 15; } \
    c_ = h4 & 255u;         if (c_ > best_) { best_ = c_; bi_ = 16; } \
    mode[OI] = (uint8_t)bi_; }
#pragma unroll
  for (int dy = 0; dy < 11; ++dy) {
#pragma unroll
    for (int dx = 0; dx < 11; ++dx) ADDV(tile[dy][t + dx]);
  }
  size_t ob = (size_t)pl * 262144 + (size_t)(rb * 32) * 512 + cb * 256 + t;
  SCAN_STORE(ob);
  for (int s = 1; s < 32; ++s) {
#pragma unroll
    for (int dx = 0; dx < 11; ++dx) { SUBV(tile[s - 1][t + dx]); ADDV(tile[s + 10][t + dx]); }
    SCAN_STORE(ob + (size_t)s * 512);
  }
#undef ADDV
#undef SUBV
#undef SCAN_STORE
}

// ---------------------------------------------------------------------------
// K2: histogram of 3-channel mode combos (17^3 = 4913 bins). grid 256.
// ---------------------------------------------------------------------------
__global__ __launch_bounds__(256) void k_hist(const uint8_t* __restrict__ mode,
                                              uint32_t* __restrict__ hist) {
  __shared__ uint32_t h[4913];
  int tid = threadIdx.x;
  for (int e = tid; e < 4913; e += 256) h[e] = 0;
  __syncthreads();
  int base = blockIdx.x * 8192;
  for (int it = 0; it < 16; ++it) {
    int px = base + it * 512 + tid * 2;
    int b = px >> 18, rem = px & 262143;
    const uint8_t* mp = mode + (size_t)b * 786432 + rem;
    uint32_t m0 = *(const uint16_t*)(mp);
    uint32_t m1 = *(const uint16_t*)(mp + 262144);
    uint32_t m2 = *(const uint16_t*)(mp + 524288);
    int c0 = (int)(m0 & 255u) + 17 * (int)(m1 & 255u) + 289 * (int)(m2 & 255u);
    int c1 = (int)(m0 >> 8)   + 17 * (int)(m1 >> 8)   + 289 * (int)(m2 >> 8);
    atomicAdd(&h[c0], 1u);
    atomicAdd(&h[c1], 1u);
  }
  __syncthreads();
  for (int e = tid; e < 4913; e += 256)
    if (h[e]) atomicAdd(&hist[e], h[e]);
}

// ---------------------------------------------------------------------------
// K3: one-block build: pre1 moments -> BN1 -> h1 moments -> BN2 -> LUT + prep
//     moments. Everything weighted by the combo histogram.
// ---------------------------------------------------------------------------
__global__ __launch_bounds__(256) void k_build(const uint32_t* __restrict__ hist,
    const float* __restrict__ pw1, const float* __restrict__ pb1,
    const float* __restrict__ g1,  const float* __restrict__ be1,
    const float* __restrict__ pw2, const float* __restrict__ pb2,
    const float* __restrict__ g2,  const float* __restrict__ be2,
    float* __restrict__ stats, uint32_t* __restrict__ lut) {
  __shared__ float red[4 * 152];
  int tid = threadIdx.x;
  // ---- phase A: pre1 = pw1*xq + pb1 moments ----
  {
    float acc[32];
#pragma unroll
    for (int k = 0; k < 32; ++k) acc[k] = 0.f;
    for (int bin = tid; bin < 4913; bin += 256) {
      float w = (float)hist[bin];
      if (w == 0.f) continue;
      int m0 = bin % 17, r = bin / 17;
      int m1 = r % 17, m2 = r / 17;
      float x0 = m0 * 0.0625f, x1 = m1 * 0.0625f, x2 = m2 * 0.0625f;
#pragma unroll
      for (int o = 0; o < 16; ++o) {
        float p = fmaf(pw1[o * 3], x0, fmaf(pw1[o * 3 + 1], x1, fmaf(pw1[o * 3 + 2], x2, pb1[o])));
        acc[o] = fmaf(w, p, acc[o]);
        acc[16 + o] = fmaf(w * p, p, acc[16 + o]);
      }
    }
    block_red<32, false>(acc, stats + S_PRE1, red);
  }
  __syncthreads();
  if (tid < 16) {  // BN1 affine
    int o = tid;
    float m = stats[S_PRE1 + o] * NINV;
    float var = stats[S2_PRE1 + o] * NINV - m * m;
    float s = g1[o] * rsqrtf(var + 1e-5f);
    stats[P_A1 + o * 3 + 0] = pw1[o * 3 + 0] * s;
    stats[P_A1 + o * 3 + 1] = pw1[o * 3 + 1] * s;
    stats[P_A1 + o * 3 + 2] = pw1[o * 3 + 2] * s;
    stats[P_B1 + o] = (pb1[o] - m) * s + be1[o];
  }
  __syncthreads();
  // ---- phase B: h1 moments (16 sums + 136 upper-tri) ----
  {
    float acc[152];
#pragma unroll
    for (int k = 0; k < 152; ++k) acc[k] = 0.f;
    for (int bin = tid; bin < 4913; bin += 256) {
      float w = (float)hist[bin];
      if (w == 0.f) continue;
      int m0 = bin % 17, r = bin / 17;
      int m1 = r % 17, m2 = r / 17;
      float x0 = m0 * 0.0625f, x1 = m1 * 0.0625f, x2 = m2 * 0.0625f;
      float h[16];
#pragma unroll
      for (int c = 0; c < 16; ++c) {
        float y = fmaf(stats[P_A1 + c * 3], x0, fmaf(stats[P_A1 + c * 3 + 1], x1,
                  fmaf(stats[P_A1 + c * 3 + 2], x2, stats[P_B1 + c])));
        h[c] = fmaxf(y, 0.01f * y);
        acc[c] = fmaf(w, h[c], acc[c]);
      }
#pragma unroll
      for (int c = 0; c < 16; ++c) {
#pragma unroll
        for (int c2 = c; c2 < 16; ++c2) {
          int idx = 16 * c - (c * (c - 1)) / 2 + (c2 - c);
          acc[16 + idx] = fmaf(w * h[c], h[c2], acc[16 + idx]);
        }
      }
    }
    block_red<152, false>(acc, stats + S_H1, red);
  }
  __syncthreads();
  if (tid < 16) {  // BN2 affine
    int o = tid;
    float s1 = 0.f;
#pragma unroll
    for (int c = 0; c < 16; ++c) s1 = fmaf(pw2[o * 16 + c], stats[S_H1 + c] * NINV, s1);
    float e2 = 0.f;
#pragma unroll
    for (int c = 0; c < 16; ++c) {
#pragma unroll
      for (int c2 = 0; c2 < 16; ++c2) {
        int lo = c < c2 ? c : c2, hi = c < c2 ? c2 : c;
        int idx = 16 * lo - (lo * (lo - 1)) / 2 + (hi - lo);
        e2 = fmaf(pw2[o * 16 + c] * pw2[o * 16 + c2], stats[S_H1H1 + idx] * NINV, e2);
      }
    }
    float var = e2 - s1 * s1;
    float mean = s1 + pb2[o];
    float s = g2[o] * rsqrtf(var + 1e-5f);
#pragma unroll
    for (int c = 0; c < 16; ++c) stats[P_A2 + o * 16 + c] = pw2[o * 16 + c] * s;
    stats[P_B2 + o] = (pb2[o] - mean) * s + be2[o];
  }
  __syncthreads();
  // ---- phase C: LUT (bf16-packed prep per combo) + prep moments ----
  {
    float acc[32];
#pragma unroll
    for (int k = 0; k < 32; ++k) acc[k] = 0.f;
    for (int bin = tid; bin < 4913; bin += 256) {
      float w = (float)hist[bin];
      int m0 = bin % 17, r = bin / 17;
      int m1 = r % 17, m2 = r / 17;
      float x0 = m0 * 0.0625f, x1 = m1 * 0.0625f, x2 = m2 * 0.0625f;
      float h[16];
#pragma unroll
      for (int c = 0; c < 16; ++c) {
        float y = fmaf(stats[P_A1 + c * 3], x0, fmaf(stats[P_A1 + c * 3 + 1], x1,
                  fmaf(stats[P_A1 + c * 3 + 2], x2, stats[P_B1 + c])));
        h[c] = fmaxf(y, 0.01f * y);
      }
      float p[16];
#pragma unroll
      for (int o = 0; o < 16; ++o) {
        float y = stats[P_B2 + o];
#pragma unroll
        for (int c = 0; c < 16; ++c) y = fmaf(stats[P_A2 + o * 16 + c], h[c], y);
        p[o] = fmaxf(y, 0.01f * y);
        acc[o] = fmaf(w, p[o], acc[o]);
        acc[16 + o] = fmaf(w * p[o], p[o], acc[16 + o]);
      }
#pragma unroll
      for (int d = 0; d < 8; ++d)
        lut[bin * 8 + d] = f2bf(p[2 * d]) | (f2bf(p[2 * d + 1]) << 16);
    }
    block_red<32, false>(acc, stats + S_PREP, red);
  }
}

// ---------------------------------------------------------------------------
// K4: prep materialization = pure LUT gather. grid 4096 = (b, row j).
// ---------------------------------------------------------------------------
__global__ __launch_bounds__(256) void k_prep(const uint8_t* __restrict__ mode,
                                              const uint32_t* __restrict__ lut,
                                              uint32_t* __restrict__ prep32) {
  int bx = blockIdx.x; int b = bx >> 9, j = bx & 511;
  int i0 = threadIdx.x * 2;
  int rem = j * 512 + i0;
  const uint8_t* mp = mode + (size_t)b * 786432 + rem;
  uint32_t m0 = *(const uint16_t*)(mp);
  uint32_t m1 = *(const uint16_t*)(mp + 262144);
  uint32_t m2 = *(const uint16_t*)(mp + 524288);
  int ca = (int)(m0 & 255u) + 17 * (int)(m1 & 255u) + 289 * (int)(m2 & 255u);
  int cb = (int)(m0 >> 8)   + 17 * (int)(m1 >> 8)   + 289 * (int)(m2 >> 8);
  const uint4* La = (const uint4*)(lut + ca * 8);
  const uint4* Lb = (const uint4*)(lut + cb * 8);
  uint4 a0 = La[0], a1 = La[1], b0 = Lb[0], b1 = Lb[1];
  uint32_t pa[8] = {a0.x, a0.y, a0.z, a0.w, a1.x, a1.y, a1.z, a1.w};
  uint32_t pb[8] = {b0.x, b0.y, b0.z, b0.w, b1.x, b1.y, b1.z, b1.w};
  size_t obase = ((size_t)(b * 16) * 512 + j) * 512 + i0;  // halfword units
#pragma unroll
  for (int c = 0; c < 16; ++c) {
    uint32_t lo = (c & 1) ? (pa[c >> 1] >> 16)      : (pa[c >> 1] & 0xFFFFu);
    uint32_t hi = (c & 1) ? (pb[c >> 1] & 0xFFFF0000u) : (pb[c >> 1] << 16);
    prep32[(obase + (size_t)c * 262144) >> 1] = lo | hi;
  }
}

// ---------------------------------------------------------------------------
// K5: conv 3x3 stride 3 pad 1, 16->16 channels. One block per (b, out row).
// ---------------------------------------------------------------------------
template<bool BF> struct itype { using T = float; };
template<> struct itype<true> { using T = uint16_t; };

template<int HIN, int WIN, int HOUT, int WOUT, bool BF>
__global__ __launch_bounds__(256) void k_conv(const void* __restrict__ inv,
                                              float* __restrict__ out,
                                              const float* __restrict__ dw) {
  using IT = typename itype<BF>::T;
  const IT* in = (const IT*)inv;
  __shared__ IT tile[3][16][WIN + 2];
  int bx = blockIdx.x; int r = bx % HOUT, b = bx / HOUT;
  int tid = threadIdx.x;
  for (int e = tid; e < 48; e += 256) { tile[e / 16][e & 15][0] = (IT)0; tile[e / 16][e & 15][WIN + 1] = (IT)0; }
  for (int e = tid; e < 3 * 16 * WIN; e += 256) {
    int ky = e / (16 * WIN); int rem = e - ky * (16 * WIN); int ic = rem / WIN; int col = rem - ic * WIN;
    int gr = 3 * r - 1 + ky;
    IT v = (IT)0;
    if (gr >= 0 && gr < HIN) v = in[((size_t)(b * 16 + ic) * HIN + gr) * WIN + col];
    tile[ky][ic][col + 1] = v;
  }
  __syncthreads();
  int c = tid;
  if (c < WOUT) {
    float acc[16];
#pragma unroll
    for (int o = 0; o < 16; ++o) acc[o] = 0.f;
#pragma unroll
    for (int ic = 0; ic < 16; ++ic) {
      float v[9];
#pragma unroll
      for (int ky = 0; ky < 3; ++ky) {
#pragma unroll
        for (int kx = 0; kx < 3; ++kx) {
          IT raw = tile[ky][ic][3 * c + kx];
          if constexpr (BF) v[ky * 3 + kx] = __uint_as_float(((uint32_t)raw) << 16);
          else              v[ky * 3 + kx] = (float)raw;
        }
      }
#pragma unroll
      for (int o = 0; o < 16; ++o) {
        const float* w = dw + (o * 16 + ic) * 9;
#pragma unroll
        for (int tp = 0; tp < 9; ++tp) acc[o] = fmaf(v[tp], w[tp], acc[o]);
      }
    }
#pragma unroll
    for (int o = 0; o < 16; ++o)
      out[((size_t)(b * 16 + o) * HOUT + r) * WOUT + c] = acc[o];
  }
}

// ---------------------------------------------------------------------------
// K6: level-1 stats: Sz1, Sz1^2, S(prep*z1) over dst grid. grid 512.
// ---------------------------------------------------------------------------
__global__ __launch_bounds__(256) void k_corr1(const uint16_t* __restrict__ prep,
                                               const float* __restrict__ d1,
                                               float* __restrict__ stats) {
  int bx = blockIdx.x; int b = bx >> 6, band = bx & 63;
  float acc[48];
#pragma unroll
  for (int k = 0; k < 48; ++k) acc[k] = 0.f;
  for (int jj = 0; jj < 8; ++jj) {
    int j = band * 8 + jj;
    int r1 = (j * 171) >> 9;
    for (int i = threadIdx.x; i < 512; i += 256) {
      int c1 = (i * 171) >> 9;
#pragma unroll
      for (int g = 0; g < 16; ++g) {
        float p = bf2f(prep[((size_t)(b * 16 + g) * 512 + j) * 512 + i]);
        float z = d1[((size_t)(b * 16 + g) * 171 + r1) * 171 + c1];
        acc[g] += z; acc[16 + g] = fmaf(z, z, acc[16 + g]); acc[32 + g] = fmaf(p, z, acc[32 + g]);
      }
    }
  }
  __shared__ float red[4 * 48];
  block_red<48, true>(acc, stats + S_Z1, red);
}

// ---------------------------------------------------------------------------
// K7: pair stats for level l>=2: Sz, Sz^2, S(z_{l-1} z_l) over dst grid.
// ---------------------------------------------------------------------------
template<int HP, int HZ>
__global__ __launch_bounds__(256) void k_pair(const float* __restrict__ dp,
                                              const float* __restrict__ dz,
                                              float* __restrict__ dst) {
  int bx = blockIdx.x;
  int g = bx & 15, b = (bx >> 4) & 7, jq = bx >> 7;
  const float* dpp = dp + (size_t)(b * 16 + g) * HP * HP;
  const float* dzp = dz + (size_t)(b * 16 + g) * HZ * HZ;
  float a1 = 0.f, a2 = 0.f, a3 = 0.f;
  for (int j = jq * 128; j < jq * 128 + 128; ++j) {
    int r1 = (j * HP) >> 9, r2 = (j * HZ) >> 9;
    const float* rp = dpp + r1 * HP;
    const float* rz = dzp + r2 * HZ;
    for (int i = threadIdx.x; i < 512; i += 256) {
      int c1 = (i * HP) >> 9, c2 = (i * HZ) >> 9;
      float zp = rp[c1], zz = rz[c2];
      a1 += zz; a2 = fmaf(zz, zz, a2); a3 = fmaf(zp, zz, a3);
    }
  }
  a1 = wave_red(a1); a2 = wave_red(a2); a3 = wave_red(a3);
  __shared__ float red[12];
  int lane = threadIdx.x & 63, wid = threadIdx.x >> 6;
  if (!lane) { red[wid * 3] = a1; red[wid * 3 + 1] = a2; red[wid * 3 + 2] = a3; }
  __syncthreads();
  if (threadIdx.x < 3) {
    float s = red[threadIdx.x] + red[3 + threadIdx.x] + red[6 + threadIdx.x] + red[9 + threadIdx.x];
    atomicAdd(&dst[threadIdx.x * 16 + g], s);
  }
}

// K8: per-level BN affine: a0=s*sw0, a1=s*sw1, b = bs - mean*s
__global__ void k_bnLprep(float* stats, const float* sw, const float* gs, const float* bs) {
  int t = threadIdx.x; if (t >= 192) return;
  int lvl = t >> 5, ch = t & 31, g = ch >> 1, o = ch & 1;
  float Sp, Sp2, Sz, Sz2, Spz;
  if (lvl == 0) {
    Sp = stats[S_PREP + g]; Sp2 = stats[S2_PREP + g];
    Sz = stats[S_Z1 + g];   Sz2 = stats[S2_Z1 + g]; Spz = stats[S_PZ1 + g];
  } else {
    int base = S_LVLBASE + (lvl - 1) * 48;
    Sz = stats[base + g]; Sz2 = stats[base + 16 + g]; Spz = stats[base + 32 + g];
    if (lvl == 1) { Sp = stats[S_Z1 + g]; Sp2 = stats[S2_Z1 + g]; }
    else { int pb = S_LVLBASE + (lvl - 2) * 48; Sp = stats[pb + g]; Sp2 = stats[pb + 16 + g]; }
  }
  float mp = Sp * NINV, mz = Sz * NINV;
  float ep2 = Sp2 * NINV, ez2 = Sz2 * NINV, epz = Spz * NINV;
  float w0 = sw[g * 4 + o * 2], w1 = sw[g * 4 + o * 2 + 1];
  float mean = w0 * mp + w1 * mz;
  float e2 = w0 * w0 * ep2 + 2.f * w0 * w1 * epz + w1 * w1 * ez2;
  float var = e2 - mean * mean;
  float s = gs[ch] * rsqrtf(var + 1e-5f);
  float* a = stats + P_AFF + (lvl * 32 + ch) * 3;
  a[0] = s * w0; a[1] = s * w1; a[2] = bs[ch] - mean * s;
}

// ---------------------------------------------------------------------------
// K9: fused score: all 6 levels, one pass. grid 4096 = (b, row j).
// Wave-per-g mapping: affine coeffs live in registers across the whole row.
// ---------------------------------------------------------------------------
__global__ __launch_bounds__(256) void k_score(const uint16_t* __restrict__ prep,
    const float* __restrict__ d1, const float* __restrict__ d2, const float* __restrict__ d3,
    const float* __restrict__ d4, const float* __restrict__ d5, const float* __restrict__ d6,
    const float* __restrict__ stats, float* __restrict__ out) {
  __shared__ float zrow[4128];
  __shared__ float aff[576];
  int bx = blockIdx.x; int b = bx >> 9, j = bx & 511;
  int tid = threadIdx.x;
  for (int e = tid; e < 576; e += 256) aff[e] = stats[P_AFF + e];
  { int r = (j * 171) >> 9; for (int e = tid; e < 16 * 171; e += 256) { int g = e / 171, c = e - g * 171; zrow[e]        = d1[((size_t)(b * 16 + g) * 171 + r) * 171 + c]; } }
  { int r = (j * 57)  >> 9; for (int e = tid; e < 16 * 57;  e += 256) { int g = e / 57,  c = e - g * 57;  zrow[2736 + e] = d2[((size_t)(b * 16 + g) * 57  + r) * 57  + c]; } }
  { int r = (j * 19)  >> 9; for (int e = tid; e < 16 * 19;  e += 256) { int g = e / 19,  c = e - g * 19;  zrow[3648 + e] = d3[((size_t)(b * 16 + g) * 19  + r) * 19  + c]; } }
  { int r = (j * 7)   >> 9; for (int e = tid; e < 16 * 7;   e += 256) { int g = e / 7,   c = e - g * 7;   zrow[3952 + e] = d4[((size_t)(b * 16 + g) * 7   + r) * 7   + c]; } }
  { int r = (j * 3)   >> 9; for (int e = tid; e < 16 * 3;   e += 256) { int g = e / 3,   c = e - g * 3;   zrow[4064 + e] = d5[((size_t)(b * 16 + g) * 3   + r) * 3   + c]; } }
  { for (int e = tid; e < 16; e += 256) zrow[4112 + e] = d6[b * 16 + e]; }
  __syncthreads();
  int wave = tid >> 6, lane = tid & 63;
#pragma unroll
  for (int gi = 0; gi < 4; ++gi) {
    int g = wave * 4 + gi;
    float A[36];
#pragma unroll
    for (int l = 0; l < 6; ++l) {
#pragma unroll
      for (int q = 0; q < 6; ++q) A[l * 6 + q] = aff[(l * 32 + 2 * g) * 3 + q];
    }
    float z6 = zrow[4112 + g];
    const uint16_t* prow = prep + ((size_t)(b * 16 + g) * 512 + j) * 512;
    float* orow = out + ((size_t)(b * 32 + 2 * g) * 512 + j) * 512;
    const float* z1p = zrow + g * 171;
    const float* z2p = zrow + 2736 + g * 57;
    const float* z3p = zrow + 3648 + g * 19;
    const float* z4p = zrow + 3952 + g * 7;
    const float* z5p = zrow + 4064 + g * 3;
#pragma unroll
    for (int k = 0; k < 4; ++k) {
      int i = (lane << 1) + (k << 7);
      uint32_t pv = *(const uint32_t*)(prow + i);
      float pA = bf2f(pv & 0xFFFFu), pB = bf2f(pv >> 16);
      int ib = i + 1;
      float za1 = z1p[(i * 171) >> 9], zb1 = z1p[(ib * 171) >> 9];
      float za2 = z2p[(i * 57) >> 9],  zb2 = z2p[(ib * 57) >> 9];
      float za3 = z3p[(i * 19) >> 9],  zb3 = z3p[(ib * 19) >> 9];
      float za4 = z4p[(i * 7) >> 9],   zb4 = z4p[(ib * 7) >> 9];
      float za5 = z5p[(i * 3) >> 9],   zb5 = z5p[(ib * 3) >> 9];
      float o0a = 0.f, o1a = 0.f, prevA = pA;
      float o0b = 0.f, o1b = 0.f, prevB = pB;
#define ST(L, ZA, ZB) { float y_; \
      y_ = fmaf(A[L*6+0], prevA, fmaf(A[L*6+1], (ZA), A[L*6+2])); o0a += fmaxf(y_, 0.01f * y_); \
      y_ = fmaf(A[L*6+3], prevA, fmaf(A[L*6+4], (ZA), A[L*6+5])); o1a += fmaxf(y_, 0.01f * y_); \
      y_ = fmaf(A[L*6+0], prevB, fmaf(A[L*6+1], (ZB), A[L*6+2])); o0b += fmaxf(y_, 0.01f * y_); \
      y_ = fmaf(A[L*6+3], prevB, fmaf(A[L*6+4], (ZB), A[L*6+5])); o1b += fmaxf(y_, 0.01f * y_); \
      prevA = (ZA); prevB = (ZB); }
      ST(0, za1, zb1) ST(1, za2, zb2) ST(2, za3, zb3) ST(3, za4, zb4) ST(4, za5, zb5) ST(5, z6, z6)
#undef ST
      float2 s0 = make_float2(o0a, o0b);
      float2 s1 = make_float2(o1a, o1b);
      *(float2*)(orow + i) = s0;
      *(float2*)(orow + 262144 + i) = s1;
    }
  }
}

// ---------------------------------------------------------------------------
extern "C" void kernel_launch(void* const* d_in, const int* in_sizes, int n_in,
                              void* d_out, int out_size, void* d_ws, size_t ws_size,
                              hipStream_t stream) {
  const float* x   = (const float*)d_in[0];
  const float* pw1 = (const float*)d_in[1];
  const float* pb1 = (const float*)d_in[2];
  const float* g1  = (const float*)d_in[3];
  const float* be1 = (const float*)d_in[4];
  const float* pw2 = (const float*)d_in[5];
  const float* pb2 = (const float*)d_in[6];
  const float* g2  = (const float*)d_in[7];
  const float* be2 = (const float*)d_in[8];
  const float* dw  = (const float*)d_in[9];
  const float* sw  = (const float*)d_in[10];
  const float* gs  = (const float*)d_in[11];
  const float* bs  = (const float*)d_in[12];
  char* ws = (char*)d_ws;
  float*    stats = (float*)(ws + OFF_STATS);
  uint32_t* hist  = (uint32_t*)(ws + OFF_HIST);
  uint32_t* lut   = (uint32_t*)(ws + OFF_LUT);
  uint8_t*  mode  = (uint8_t*)(ws + OFF_MODE);
  uint16_t* prep  = (uint16_t*)(ws + OFF_PREP);
  float* d1 = (float*)(ws + OFF_D1);
  float* d2 = (float*)(ws + OFF_D2);
  float* d3 = (float*)(ws + OFF_D3);
  float* d4 = (float*)(ws + OFF_D4);
  float* d5 = (float*)(ws + OFF_D5);
  float* d6 = (float*)(ws + OFF_D6);
  float* out = (float*)d_out;

  hipMemsetAsync(ws, 0, 36864, stream);  // stats + hist
  k_mode<<<768, 256, 0, stream>>>(x, mode);
  k_hist<<<256, 256, 0, stream>>>(mode, hist);
  k_build<<<1, 256, 0, stream>>>(hist, pw1, pb1, g1, be1, pw2, pb2, g2, be2, stats, lut);
  k_prep<<<4096, 256, 0, stream>>>(mode, lut, (uint32_t*)prep);
  k_conv<512, 512, 171, 171, true><<<8 * 171, 256, 0, stream>>>(prep, d1, dw);
  k_corr1<<<512, 256, 0, stream>>>(prep, d1, stats);
  k_conv<171, 171, 57, 57, false><<<8 * 57, 256, 0, stream>>>(d1, d2, dw);
  k_pair<171, 57><<<512, 256, 0, stream>>>(d1, d2, stats + S_LVLBASE + 0 * 48);
  k_conv<57, 57, 19, 19, false><<<8 * 19, 256, 0, stream>>>(d2, d3, dw);
  k_pair<57, 19><<<512, 256, 0, stream>>>(d2, d3, stats + S_LVLBASE + 1 * 48);
  k_conv<19, 19, 7, 7, false><<<8 * 7, 256, 0, stream>>>(d3, d4, dw);
  k_pair<19, 7><<<512, 256, 0, stream>>>(d3, d4, stats + S_LVLBASE + 2 * 48);
  k_conv<7, 7, 3, 3, false><<<8 * 3, 256, 0, stream>>>(d4, d5, dw);
  k_pair<7, 3><<<512, 256, 0, stream>>>(d4, d5, stats + S_LVLBASE + 3 * 48);
  k_conv<3, 3, 1, 1, false><<<8 * 1, 256, 0, stream>>>(d5, d6, dw);
  k_pair<3, 1><<<512, 256, 0, stream>>>(d5, d6, stats + S_LVLBASE + 4 * 48);
  k_bnLprep<<<1, 256, 0, stream>>>(stats, sw, gs, bs);
  k_score<<<4096, 256, 0, stream>>>(prep, d1, d2, d3, d4, d5, d6, stats, out);
}